// Round 2
// baseline (313.317 us; speedup 1.0000x reference)
//
#include <hip/hip_runtime.h>
#include <stdint.h>

// Problem constants (B=8, C1=256, H=W=128)
#define B_    8
#define C1_   256
#define H_    128
#define W_    128
#define H2_   64
#define HW_   4096   // H2*W2
#define KDIM  1024   // fused channels = C1 (LL) + 3*C1 (hf)
#define C2_   512
#define MID_  48
#define CHF_  768    // 3*C1

typedef __attribute__((ext_vector_type(8))) short short8;    // 8 bf16 (4 VGPRs)
typedef __attribute__((ext_vector_type(16))) float f32x16;   // 32x32 MFMA acc

__device__ __forceinline__ unsigned short f2bf(float f) {
  unsigned int u = __float_as_uint(f);
  u += 0x7fffu + ((u >> 16) & 1u);   // round-to-nearest-even
  return (unsigned short)(u >> 16);
}
__device__ __forceinline__ float bf2f(unsigned short h) {
  return __uint_as_float(((unsigned int)h) << 16);
}

// ---------------------------------------------------------------------------
// K1: Haar wavelet -> fused_t (bf16, [b][hw][ch], ch K-contiguous) + per-block
// hf channel sums (plain stores; k2 reduces). float4 reads: 32 lanes cover a
// full 128-wide row; each thread produces 2 output pixels per channel.
// ---------------------------------------------------------------------------
__global__ __launch_bounds__(256) void k1_wavelet(const float* __restrict__ x,
                                                  unsigned short* __restrict__ fused_t,
                                                  float* __restrict__ chanSums) {
  __shared__ unsigned short ll_s[64 * 66];   // [w2][ch-chunk], stride 66 u16
  __shared__ unsigned short hf_s[64 * 198];  // [w2][3*ch-chunk], stride 198 u16
  const int tid = threadIdx.x;
  const int h2 = blockIdx.x;
  const int b  = blockIdx.y;
  const int w4 = tid & 31;   // 32 lanes x float4 = full 128-wide row
  const int grp = tid >> 5;  // 8 channel groups
  const float* xb = x + (size_t)b * C1_ * H_ * W_;
  const size_t rowbase = ((size_t)b * HW_ + (size_t)h2 * 64) * KDIM;

  for (int q = 0; q < 4; ++q) {            // 4 chunks of 64 src channels
#pragma unroll
    for (int i = 0; i < 8; ++i) {
      int cl = grp * 8 + i;
      int c  = q * 64 + cl;
      const float* xp = xb + (size_t)c * (H_ * W_) + (2 * h2) * W_ + 4 * w4;
      float4 r0 = *(const float4*)xp;          // x00a,x01a,x00b,x01b
      float4 r1 = *(const float4*)(xp + W_);   // x10a,x11a,x10b,x11b
      // pixel a: w2 = 2*w4
      {
        float x00 = r0.x, x01 = r0.y, x10 = r1.x, x11 = r1.y;
        float LL = 0.5f * (x00 + x01 + x10 + x11);
        float LH = 0.5f * (x00 + x01 - x10 - x11);
        float HL = 0.5f * (x00 - x01 + x10 - x11);
        float HH = 0.5f * (x00 - x01 - x10 + x11);
        int w2 = 2 * w4;
        ll_s[w2 * 66 + cl]          = f2bf(LL);
        hf_s[w2 * 198 + 3 * cl + 0] = f2bf(LH);
        hf_s[w2 * 198 + 3 * cl + 1] = f2bf(HL);
        hf_s[w2 * 198 + 3 * cl + 2] = f2bf(HH);
      }
      // pixel b: w2 = 2*w4+1
      {
        float x00 = r0.z, x01 = r0.w, x10 = r1.z, x11 = r1.w;
        float LL = 0.5f * (x00 + x01 + x10 + x11);
        float LH = 0.5f * (x00 + x01 - x10 - x11);
        float HL = 0.5f * (x00 - x01 + x10 - x11);
        float HH = 0.5f * (x00 - x01 - x10 + x11);
        int w2 = 2 * w4 + 1;
        ll_s[w2 * 66 + cl]          = f2bf(LL);
        hf_s[w2 * 198 + 3 * cl + 0] = f2bf(LH);
        hf_s[w2 * 198 + 3 * cl + 1] = f2bf(HL);
        hf_s[w2 * 198 + 3 * cl + 2] = f2bf(HH);
      }
    }
    __syncthreads();
    // copy LL chunk out: 64 rows x 64 ch (128 B/row) = 2048 u32
    {
      const unsigned int* lw = (const unsigned int*)ll_s;
#pragma unroll
      for (int t = 0; t < 8; ++t) {
        int idx = t * 256 + tid;
        int row = idx >> 5, w = idx & 31;
        unsigned int v = lw[row * 33 + w];
        *(unsigned int*)((char*)(fused_t + rowbase + (size_t)row * KDIM + q * 64) + w * 4) = v;
      }
    }
    // copy HF chunk out: 64 rows x 192 ch (384 B/row) = 6144 u32
    {
      const unsigned int* hv = (const unsigned int*)hf_s;
#pragma unroll
      for (int t = 0; t < 24; ++t) {
        int idx = t * 256 + tid;
        int row = idx / 96, w = idx - row * 96;
        unsigned int v = hv[row * 99 + w];
        *(unsigned int*)((char*)(fused_t + rowbase + (size_t)row * KDIM + 256 + q * 192) + w * 4) = v;
      }
    }
    // hf channel partial sums for this block (no atomics; k2 reduces)
    if (tid < 192) {
      float s = 0.f;
#pragma unroll 8
      for (int r = 0; r < 64; ++r) s += bf2f(hf_s[r * 198 + tid]);
      chanSums[((size_t)(b * 64 + h2)) * CHF_ + q * 192 + tid] = s;
    }
    __syncthreads();
  }
}

// ---------------------------------------------------------------------------
// K2: reduce chanSums -> mean; SE MLP; scale array; BN affine precompute.
// One block per batch.
// ---------------------------------------------------------------------------
__global__ __launch_bounds__(256) void k2_mlp(const float* __restrict__ chanSums,
                                              const float* __restrict__ w1,
                                              const float* __restrict__ w2,
                                              const float* __restrict__ gamma,
                                              const float* __restrict__ beta,
                                              const float* __restrict__ mean,
                                              const float* __restrict__ var,
                                              float* __restrict__ scaleArr,
                                              float* __restrict__ bnA,
                                              float* __restrict__ bnB) {
  __shared__ float mean_s[CHF_];
  __shared__ float part_s[192];
  __shared__ float y1_s[MID_];
  const int tid = threadIdx.x;
  const int b = blockIdx.x;
  for (int k = tid; k < CHF_; k += 256) {
    float s = 0.f;
#pragma unroll 8
    for (int h2 = 0; h2 < 64; ++h2)
      s += chanSums[((size_t)(b * 64 + h2)) * CHF_ + k];
    mean_s[k] = s * (1.0f / 4096.0f);
  }
  __syncthreads();
  if (tid < 192) {  // 4 threads per output m, 192-deep partials
    int m = tid >> 2, p = tid & 3;
    const float* wr = w1 + (size_t)m * CHF_ + p * 192;
    const float* ms = mean_s + p * 192;
    float s = 0.f;
#pragma unroll 8
    for (int k = 0; k < 192; ++k) s += ms[k] * wr[k];
    part_s[tid] = s;
  }
  __syncthreads();
  if (tid < MID_) {
    float s = part_s[4 * tid] + part_s[4 * tid + 1] + part_s[4 * tid + 2] + part_s[4 * tid + 3];
    y1_s[tid] = fmaxf(s, 0.f);
  }
  __syncthreads();
  for (int c = tid; c < CHF_; c += 256) {
    const float* wr = w2 + (size_t)c * MID_;
    float d = 0.f;
#pragma unroll
    for (int m = 0; m < MID_; ++m) d += y1_s[m] * wr[m];
    scaleArr[b * KDIM + 256 + c] = 1.0f / (1.0f + __expf(-d));
  }
  scaleArr[b * KDIM + tid] = 1.0f;  // LL channels unscaled (tid covers 0..255)
  if (b == 0) {
    for (int o = tid; o < C2_; o += 256) {
      float inv = rsqrtf(var[o] + 1e-5f);
      float a = gamma[o] * inv;
      bnA[o] = a;
      bnB[o] = beta[o] - mean[o] * a;
    }
  }
}

// ---------------------------------------------------------------------------
// K2b: fold SE scale into per-batch bf16 weights: conv_ws[b][o][c]
// ---------------------------------------------------------------------------
__global__ __launch_bounds__(256) void k2b_scalew(const float* __restrict__ conv_w,
                                                  const float* __restrict__ scaleArr,
                                                  unsigned short* __restrict__ conv_ws) {
  int idx = blockIdx.x * 256 + threadIdx.x;  // 1,048,576 groups of 4 elements
  int b = idx >> 17;
  int rem = idx & 131071;
  int o = rem >> 8;
  int c = (rem & 255) * 4;
  float4 wv = *(const float4*)(conv_w + (size_t)o * KDIM + c);
  float4 sv = *(const float4*)(scaleArr + b * KDIM + c);
  ushort4 r;
  r.x = f2bf(wv.x * sv.x);
  r.y = f2bf(wv.y * sv.y);
  r.z = f2bf(wv.z * sv.z);
  r.w = f2bf(wv.w * sv.w);
  *(ushort4*)(conv_ws + ((size_t)(b * C2_ + o) * KDIM + c)) = r;
}

// ---------------------------------------------------------------------------
// K3: per-batch GEMM  C[o][hw] = sum_c conv_ws[o][c] * fused_t[hw][c]
// (M=512, N=4096, K=1024). 128x128 tile, BK=64 (16 barrier pairs), XOR-swizzled
// LDS (128 B rows, k-block ^ row&7 applied on the global_load_lds address so
// ds_read_b128 lands on all 32 banks), 4 waves x 2x2 mfma_f32_32x32x16_bf16.
// Epilogue: BN affine + SiLU; C/D: col=lane&31 (hw), row=(reg&3)+8*(reg>>2)+4*hi.
// ---------------------------------------------------------------------------
typedef const __attribute__((address_space(1))) unsigned int* gas_u32p;
typedef __attribute__((address_space(3))) unsigned int* las_u32p;
__device__ __forceinline__ void async_ld16(const void* g, void* l) {
  __builtin_amdgcn_global_load_lds((gas_u32p)g, (las_u32p)l, 16, 0, 0);
}

__global__ __launch_bounds__(256, 2) void k3_gemm(const unsigned short* __restrict__ conv_ws,
                                                  const unsigned short* __restrict__ fused_t,
                                                  const float* __restrict__ bnA,
                                                  const float* __restrict__ bnB,
                                                  float* __restrict__ out) {
  __shared__ short As[128 * 64];  // [m][k] rows of 128 B, k-blocks XOR-swizzled
  __shared__ short Bs[128 * 64];  // [n][k] rows of 128 B
  const int tid  = threadIdx.x;
  const int lane = tid & 63;
  const int wave = tid >> 6;
  const int b  = blockIdx.z;
  const int m0 = blockIdx.y * 128;  // o tile
  const int n0 = blockIdx.x * 128;  // hw tile
  const char* Abase = (const char*)(conv_ws + (size_t)b * C2_ * KDIM);
  const char* Bbase = (const char*)(fused_t + (size_t)b * HW_ * KDIM);
  // staging: each async instr covers 8 rows (8 lanes x 16 B per 128 B row).
  // lane fetches global k-block (kb ^ rloc) into LDS slot kb of row rloc.
  const int rloc = lane >> 3;        // row within 8-row group
  const int kb   = lane & 7;         // 16 B k-block within row
  const int kbsw = kb ^ rloc;        // swizzled global k-block
  const char* gA = Abase + (size_t)(m0 + wave * 32 + rloc) * (KDIM * 2) + kbsw * 16;
  const char* gB = Bbase + (size_t)(n0 + wave * 32 + rloc) * (KDIM * 2) + kbsw * 16;
  short* lA = As + (wave * 32) * 64;
  short* lB = Bs + (wave * 32) * 64;
  const int wm = wave & 1, wn = wave >> 1;
  const int r  = lane & 31;          // fragment row (m or n)
  const int hi = lane >> 5;
  const int sw = r & 7;              // un-swizzle key for this row
  f32x16 acc[2][2] = {};

  for (int k0 = 0; k0 < KDIM; k0 += 64) {
#pragma unroll
    for (int t = 0; t < 4; ++t) {
      async_ld16(gA + (size_t)t * 8 * (KDIM * 2), lA + t * 8 * 64);
      async_ld16(gB + (size_t)t * 8 * (KDIM * 2), lB + t * 8 * 64);
    }
    gA += 128; gB += 128;
    __syncthreads();  // drains vmcnt -> LDS tiles ready
#pragma unroll
    for (int ks = 0; ks < 4; ++ks) {
      const int kbg = 2 * ks + hi;       // global k-block this fragment wants
      const int ko  = (kbg ^ sw) << 3;   // short offset within the row
      short8 af[2], bf[2];
#pragma unroll
      for (int im = 0; im < 2; ++im)
        af[im] = *(const short8*)(As + (wm * 64 + im * 32 + r) * 64 + ko);
#pragma unroll
      for (int in = 0; in < 2; ++in)
        bf[in] = *(const short8*)(Bs + (wn * 64 + in * 32 + r) * 64 + ko);
#pragma unroll
      for (int im = 0; im < 2; ++im)
#pragma unroll
        for (int in = 0; in < 2; ++in)
          acc[im][in] = __builtin_amdgcn_mfma_f32_32x32x16_bf16(af[im], bf[in], acc[im][in], 0, 0, 0);
    }
    __syncthreads();  // all waves done reading before next stage overwrites
  }

  // epilogue: BN affine + SiLU. C/D: col=lane&31 (hw), row=(reg&3)+8*(reg>>2)+4*hi
  float* outb = out + (size_t)b * C2_ * HW_;
#pragma unroll
  for (int im = 0; im < 2; ++im) {
#pragma unroll
    for (int in = 0; in < 2; ++in) {
      int hw = n0 + wn * 64 + in * 32 + r;
#pragma unroll
      for (int reg = 0; reg < 16; ++reg) {
        int o = m0 + wm * 64 + im * 32 + (reg & 3) + 8 * (reg >> 2) + 4 * hi;
        float a = bnA[o], c0 = bnB[o];
        float z = acc[im][in][reg] * a + c0;
        outb[(size_t)o * HW_ + hw] = z / (1.0f + __expf(-z));
      }
    }
  }
}

// ---------------------------------------------------------------------------
extern "C" void kernel_launch(void* const* d_in, const int* in_sizes, int n_in,
                              void* d_out, int out_size, void* d_ws, size_t ws_size,
                              hipStream_t stream) {
  const float* x      = (const float*)d_in[0];
  const float* w1     = (const float*)d_in[1];
  const float* w2     = (const float*)d_in[2];
  const float* conv_w = (const float*)d_in[3];
  const float* gamma  = (const float*)d_in[4];
  const float* beta   = (const float*)d_in[5];
  const float* mean   = (const float*)d_in[6];
  const float* var    = (const float*)d_in[7];
  float* out = (float*)d_out;

  char* ws = (char*)d_ws;
  unsigned short* fused_t = (unsigned short*)ws;                       // 64 MiB bf16 [b][hw][c]
  unsigned short* conv_ws = (unsigned short*)(ws + (size_t)67108864);  // 8 MiB bf16 [b][o][c]
  float* chanSums = (float*)(ws + (size_t)75497472);                   // 512 blocks x 768 f32
  float* scaleArr = (float*)(ws + (size_t)77070336);                   // 8x1024 f32
  float* bnA      = (float*)(ws + (size_t)77103104);                   // 512 f32
  float* bnB      = (float*)(ws + (size_t)77105152);                   // 512 f32

  k1_wavelet<<<dim3(64, 8), 256, 0, stream>>>(x, fused_t, chanSums);
  k2_mlp<<<dim3(8), 256, 0, stream>>>(chanSums, w1, w2, gamma, beta, mean, var,
                                      scaleArr, bnA, bnB);
  k2b_scalew<<<dim3(4096), 256, 0, stream>>>(conv_w, scaleArr, conv_ws);
  k3_gemm<<<dim3(32, 4, 8), 256, 0, stream>>>(conv_ws, fused_t, bnA, bnB, out);
}

// Round 3
// 308.236 us; speedup vs baseline: 1.0165x; 1.0165x over previous
//
#include <hip/hip_runtime.h>
#include <stdint.h>

// Problem constants (B=8, C1=256, H=W=128)
#define B_    8
#define C1_   256
#define H_    128
#define W_    128
#define H2_   64
#define HW_   4096   // H2*W2
#define KDIM  1024   // fused channels = C1 (LL) + 3*C1 (hf)
#define C2_   512
#define MID_  48
#define CHF_  768    // 3*C1

typedef __attribute__((ext_vector_type(8))) short short8;    // 8 bf16 (4 VGPRs)
typedef __attribute__((ext_vector_type(16))) float f32x16;   // 32x32 MFMA acc

__device__ __forceinline__ unsigned short f2bf(float f) {
  unsigned int u = __float_as_uint(f);
  u += 0x7fffu + ((u >> 16) & 1u);   // round-to-nearest-even
  return (unsigned short)(u >> 16);
}
__device__ __forceinline__ float bf2f(unsigned short h) {
  return __uint_as_float(((unsigned int)h) << 16);
}

// ---------------------------------------------------------------------------
// K1: Haar wavelet -> fused_t (bf16, [b][hw][ch], ch K-contiguous) + hf channel
// sums via atomicAdd (k2 reads them directly; no 8-CU strided reduce).
// float4 global reads (32 lanes cover a 128-wide row pair); LDS transpose with
// conflict-free odd strides (66/198) on the u16 write side; copy-out with
// dwordx4 global stores (4x fewer store instrs than round 2's u32 stores).
// ---------------------------------------------------------------------------
__global__ __launch_bounds__(256) void k1_wavelet(const float* __restrict__ x,
                                                  unsigned short* __restrict__ fused_t,
                                                  float* __restrict__ chanSums) {
  __shared__ unsigned short ll_s[64 * 66];   // [w2][ch-chunk], stride 66 u16
  __shared__ unsigned short hf_s[64 * 198];  // [w2][3*ch-chunk], stride 198 u16
  const int tid = threadIdx.x;
  const int h2 = blockIdx.x;
  const int b  = blockIdx.y;
  const int w4 = tid & 31;   // 32 lanes x float4 = full 128-wide row
  const int grp = tid >> 5;  // 8 channel groups
  const float* xb = x + (size_t)b * C1_ * H_ * W_;
  const size_t rowbase = ((size_t)b * HW_ + (size_t)h2 * 64) * KDIM;

  for (int q = 0; q < 4; ++q) {            // 4 chunks of 64 src channels
#pragma unroll
    for (int i = 0; i < 8; ++i) {
      int cl = grp * 8 + i;
      int c  = q * 64 + cl;
      const float* xp = xb + (size_t)c * (H_ * W_) + (2 * h2) * W_ + 4 * w4;
      float4 r0 = *(const float4*)xp;          // x00a,x01a,x00b,x01b
      float4 r1 = *(const float4*)(xp + W_);   // x10a,x11a,x10b,x11b
      {
        float x00 = r0.x, x01 = r0.y, x10 = r1.x, x11 = r1.y;
        float LL = 0.5f * (x00 + x01 + x10 + x11);
        float LH = 0.5f * (x00 + x01 - x10 - x11);
        float HL = 0.5f * (x00 - x01 + x10 - x11);
        float HH = 0.5f * (x00 - x01 - x10 + x11);
        int w2 = 2 * w4;
        ll_s[w2 * 66 + cl]          = f2bf(LL);
        hf_s[w2 * 198 + 3 * cl + 0] = f2bf(LH);
        hf_s[w2 * 198 + 3 * cl + 1] = f2bf(HL);
        hf_s[w2 * 198 + 3 * cl + 2] = f2bf(HH);
      }
      {
        float x00 = r0.z, x01 = r0.w, x10 = r1.z, x11 = r1.w;
        float LL = 0.5f * (x00 + x01 + x10 + x11);
        float LH = 0.5f * (x00 + x01 - x10 - x11);
        float HL = 0.5f * (x00 - x01 + x10 - x11);
        float HH = 0.5f * (x00 - x01 - x10 + x11);
        int w2 = 2 * w4 + 1;
        ll_s[w2 * 66 + cl]          = f2bf(LL);
        hf_s[w2 * 198 + 3 * cl + 0] = f2bf(LH);
        hf_s[w2 * 198 + 3 * cl + 1] = f2bf(HL);
        hf_s[w2 * 198 + 3 * cl + 2] = f2bf(HH);
      }
    }
    __syncthreads();
    // LL copy-out: 64 rows x 128 B = 512 dwordx4 stores, 2 sweeps
    {
      const unsigned int* lw = (const unsigned int*)ll_s;
#pragma unroll
      for (int t = 0; t < 2; ++t) {
        int idx = t * 256 + tid;        // 0..511
        int row = idx >> 3, s = idx & 7;
        int base = row * 33 + s * 4;
        uint4 v;
        v.x = lw[base]; v.y = lw[base + 1]; v.z = lw[base + 2]; v.w = lw[base + 3];
        *(uint4*)((char*)(fused_t + rowbase + (size_t)row * KDIM + q * 64) + s * 16) = v;
      }
    }
    // HF copy-out: 64 rows x 384 B = 1536 dwordx4 stores, 6 sweeps
    {
      const unsigned int* hv = (const unsigned int*)hf_s;
#pragma unroll
      for (int t = 0; t < 6; ++t) {
        int idx = t * 256 + tid;        // 0..1535
        int row = idx / 24, s = idx - row * 24;
        int base = row * 99 + s * 4;
        uint4 v;
        v.x = hv[base]; v.y = hv[base + 1]; v.z = hv[base + 2]; v.w = hv[base + 3];
        *(uint4*)((char*)(fused_t + rowbase + (size_t)row * KDIM + 256 + q * 192) + s * 16) = v;
      }
    }
    // hf channel sums from the LDS tile (2 B/lane consecutive -> 2-way = free)
    if (tid < 192) {
      float s = 0.f;
#pragma unroll 8
      for (int r = 0; r < 64; ++r) s += bf2f(hf_s[r * 198 + tid]);
      atomicAdd(&chanSums[b * CHF_ + q * 192 + tid], s);
    }
    __syncthreads();
  }
}

// ---------------------------------------------------------------------------
// K2: SE MLP (mean -> relu(w1) -> sigmoid(w2)) + scale array + BN affine
// precompute. One block per batch; chanSums already fully reduced by k1.
// ---------------------------------------------------------------------------
__global__ __launch_bounds__(256) void k2_mlp(const float* __restrict__ chanSums,
                                              const float* __restrict__ w1,
                                              const float* __restrict__ w2,
                                              const float* __restrict__ gamma,
                                              const float* __restrict__ beta,
                                              const float* __restrict__ mean,
                                              const float* __restrict__ var,
                                              float* __restrict__ scaleArr,
                                              float* __restrict__ bnA,
                                              float* __restrict__ bnB) {
  __shared__ float mean_s[CHF_];
  __shared__ float part_s[192];
  __shared__ float y1_s[MID_];
  const int tid = threadIdx.x;
  const int b = blockIdx.x;
  for (int k = tid; k < CHF_; k += 256)
    mean_s[k] = chanSums[b * CHF_ + k] * (1.0f / 4096.0f);
  __syncthreads();
  if (tid < 192) {  // 4 threads per output m, 192-deep partials
    int m = tid >> 2, p = tid & 3;
    const float* wr = w1 + (size_t)m * CHF_ + p * 192;
    const float* ms = mean_s + p * 192;
    float s = 0.f;
#pragma unroll 8
    for (int k = 0; k < 192; ++k) s += ms[k] * wr[k];
    part_s[tid] = s;
  }
  __syncthreads();
  if (tid < MID_) {
    float s = part_s[4 * tid] + part_s[4 * tid + 1] + part_s[4 * tid + 2] + part_s[4 * tid + 3];
    y1_s[tid] = fmaxf(s, 0.f);
  }
  __syncthreads();
  for (int c = tid; c < CHF_; c += 256) {
    const float* wr = w2 + (size_t)c * MID_;
    float d = 0.f;
#pragma unroll
    for (int m = 0; m < MID_; ++m) d += y1_s[m] * wr[m];
    scaleArr[b * KDIM + 256 + c] = 1.0f / (1.0f + __expf(-d));
  }
  scaleArr[b * KDIM + tid] = 1.0f;  // LL channels unscaled (tid covers 0..255)
  if (b == 0) {
    for (int o = tid; o < C2_; o += 256) {
      float inv = rsqrtf(var[o] + 1e-5f);
      float a = gamma[o] * inv;
      bnA[o] = a;
      bnB[o] = beta[o] - mean[o] * a;
    }
  }
}

// ---------------------------------------------------------------------------
// K2b: fold SE scale into per-batch bf16 weights: conv_ws[b][o][c]
// ---------------------------------------------------------------------------
__global__ __launch_bounds__(256) void k2b_scalew(const float* __restrict__ conv_w,
                                                  const float* __restrict__ scaleArr,
                                                  unsigned short* __restrict__ conv_ws) {
  int idx = blockIdx.x * 256 + threadIdx.x;  // 1,048,576 groups of 4 elements
  int b = idx >> 17;
  int rem = idx & 131071;
  int o = rem >> 8;
  int c = (rem & 255) * 4;
  float4 wv = *(const float4*)(conv_w + (size_t)o * KDIM + c);
  float4 sv = *(const float4*)(scaleArr + b * KDIM + c);
  ushort4 r;
  r.x = f2bf(wv.x * sv.x);
  r.y = f2bf(wv.y * sv.y);
  r.z = f2bf(wv.z * sv.z);
  r.w = f2bf(wv.w * sv.w);
  *(ushort4*)(conv_ws + ((size_t)(b * C2_ + o) * KDIM + c)) = r;
}

// ---------------------------------------------------------------------------
// K3: per-batch GEMM  C[o][hw] = sum_c conv_ws[o][c] * fused_t[hw][c]
// (M=512, N=4096, K=1024). 128x128 tile, BK=64 (16 barrier pairs), XOR-swizzled
// LDS (128 B rows, k-block ^ row&7 applied on the global_load_lds address so
// ds_read_b128 lands on all 32 banks), 4 waves x 2x2 mfma_f32_32x32x16_bf16.
// Epilogue: BN affine + SiLU; C/D: col=lane&31 (hw), row=(reg&3)+8*(reg>>2)+4*hi.
// ---------------------------------------------------------------------------
typedef const __attribute__((address_space(1))) unsigned int* gas_u32p;
typedef __attribute__((address_space(3))) unsigned int* las_u32p;
__device__ __forceinline__ void async_ld16(const void* g, void* l) {
  __builtin_amdgcn_global_load_lds((gas_u32p)g, (las_u32p)l, 16, 0, 0);
}

__global__ __launch_bounds__(256, 2) void k3_gemm(const unsigned short* __restrict__ conv_ws,
                                                  const unsigned short* __restrict__ fused_t,
                                                  const float* __restrict__ bnA,
                                                  const float* __restrict__ bnB,
                                                  float* __restrict__ out) {
  __shared__ short As[128 * 64];  // [m][k] rows of 128 B, k-blocks XOR-swizzled
  __shared__ short Bs[128 * 64];  // [n][k] rows of 128 B
  const int tid  = threadIdx.x;
  const int lane = tid & 63;
  const int wave = tid >> 6;
  const int b  = blockIdx.z;
  const int m0 = blockIdx.y * 128;  // o tile
  const int n0 = blockIdx.x * 128;  // hw tile
  const char* Abase = (const char*)(conv_ws + (size_t)b * C2_ * KDIM);
  const char* Bbase = (const char*)(fused_t + (size_t)b * HW_ * KDIM);
  // staging: each async instr covers 8 rows (8 lanes x 16 B per 128 B row).
  // lane fetches global k-block (kb ^ rloc) into LDS slot kb of row rloc.
  const int rloc = lane >> 3;        // row within 8-row group
  const int kb   = lane & 7;         // 16 B k-block within row
  const int kbsw = kb ^ rloc;        // swizzled global k-block
  const char* gA = Abase + (size_t)(m0 + wave * 32 + rloc) * (KDIM * 2) + kbsw * 16;
  const char* gB = Bbase + (size_t)(n0 + wave * 32 + rloc) * (KDIM * 2) + kbsw * 16;
  short* lA = As + (wave * 32) * 64;
  short* lB = Bs + (wave * 32) * 64;
  const int wm = wave & 1, wn = wave >> 1;
  const int r  = lane & 31;          // fragment row (m or n)
  const int hi = lane >> 5;
  const int sw = r & 7;              // un-swizzle key for this row
  f32x16 acc[2][2] = {};

  for (int k0 = 0; k0 < KDIM; k0 += 64) {
#pragma unroll
    for (int t = 0; t < 4; ++t) {
      async_ld16(gA + (size_t)t * 8 * (KDIM * 2), lA + t * 8 * 64);
      async_ld16(gB + (size_t)t * 8 * (KDIM * 2), lB + t * 8 * 64);
    }
    gA += 128; gB += 128;
    __syncthreads();  // drains vmcnt -> LDS tiles ready
#pragma unroll
    for (int ks = 0; ks < 4; ++ks) {
      const int kbg = 2 * ks + hi;       // global k-block this fragment wants
      const int ko  = (kbg ^ sw) << 3;   // short offset within the row
      short8 af[2], bf[2];
#pragma unroll
      for (int im = 0; im < 2; ++im)
        af[im] = *(const short8*)(As + (wm * 64 + im * 32 + r) * 64 + ko);
#pragma unroll
      for (int in = 0; in < 2; ++in)
        bf[in] = *(const short8*)(Bs + (wn * 64 + in * 32 + r) * 64 + ko);
#pragma unroll
      for (int im = 0; im < 2; ++im)
#pragma unroll
        for (int in = 0; in < 2; ++in)
          acc[im][in] = __builtin_amdgcn_mfma_f32_32x32x16_bf16(af[im], bf[in], acc[im][in], 0, 0, 0);
    }
    __syncthreads();  // all waves done reading before next stage overwrites
  }

  // epilogue: BN affine + SiLU. C/D: col=lane&31 (hw), row=(reg&3)+8*(reg>>2)+4*hi
  float* outb = out + (size_t)b * C2_ * HW_;
#pragma unroll
  for (int im = 0; im < 2; ++im) {
#pragma unroll
    for (int in = 0; in < 2; ++in) {
      int hw = n0 + wn * 64 + in * 32 + r;
#pragma unroll
      for (int reg = 0; reg < 16; ++reg) {
        int o = m0 + wm * 64 + im * 32 + (reg & 3) + 8 * (reg >> 2) + 4 * hi;
        float a = bnA[o], c0 = bnB[o];
        float z = acc[im][in][reg] * a + c0;
        outb[(size_t)o * HW_ + hw] = z / (1.0f + __expf(-z));
      }
    }
  }
}

// ---------------------------------------------------------------------------
extern "C" void kernel_launch(void* const* d_in, const int* in_sizes, int n_in,
                              void* d_out, int out_size, void* d_ws, size_t ws_size,
                              hipStream_t stream) {
  const float* x      = (const float*)d_in[0];
  const float* w1     = (const float*)d_in[1];
  const float* w2     = (const float*)d_in[2];
  const float* conv_w = (const float*)d_in[3];
  const float* gamma  = (const float*)d_in[4];
  const float* beta   = (const float*)d_in[5];
  const float* mean   = (const float*)d_in[6];
  const float* var    = (const float*)d_in[7];
  float* out = (float*)d_out;

  char* ws = (char*)d_ws;
  unsigned short* fused_t = (unsigned short*)ws;                       // 64 MiB bf16 [b][hw][c]
  unsigned short* conv_ws = (unsigned short*)(ws + (size_t)67108864);  // 8 MiB bf16 [b][o][c]
  float* chanSums = (float*)(ws + (size_t)75497472);                   // 8x768 f32
  float* scaleArr = (float*)(ws + (size_t)75522048);                   // 8x1024 f32
  float* bnA      = (float*)(ws + (size_t)75554816);                   // 512 f32
  float* bnB      = (float*)(ws + (size_t)75556864);                   // 512 f32

  hipMemsetAsync(chanSums, 0, B_ * CHF_ * sizeof(float), stream);
  k1_wavelet<<<dim3(64, 8), 256, 0, stream>>>(x, fused_t, chanSums);
  k2_mlp<<<dim3(8), 256, 0, stream>>>(chanSums, w1, w2, gamma, beta, mean, var,
                                      scaleArr, bnA, bnB);
  k2b_scalew<<<dim3(4096), 256, 0, stream>>>(conv_w, scaleArr, conv_ws);
  k3_gemm<<<dim3(32, 4, 8), 256, 0, stream>>>(conv_ws, fused_t, bnA, bnB, out);
}

// Round 4
// 297.268 us; speedup vs baseline: 1.0540x; 1.0369x over previous
//
#include <hip/hip_runtime.h>
#include <stdint.h>

// Problem constants (B=8, C1=256, H=W=128)
#define B_    8
#define C1_   256
#define H_    128
#define W_    128
#define H2_   64
#define HW_   4096   // H2*W2
#define KDIM  1024   // fused channels = C1 (LL) + 3*C1 (hf)
#define C2_   512
#define MID_  48
#define CHF_  768    // 3*C1

typedef __attribute__((ext_vector_type(8))) short short8;    // 8 bf16 (4 VGPRs)
typedef __attribute__((ext_vector_type(16))) float f32x16;   // 32x32 MFMA acc

__device__ __forceinline__ unsigned short f2bf(float f) {
  unsigned int u = __float_as_uint(f);
  u += 0x7fffu + ((u >> 16) & 1u);   // round-to-nearest-even
  return (unsigned short)(u >> 16);
}
__device__ __forceinline__ float bf2f(unsigned short h) {
  return __uint_as_float(((unsigned int)h) << 16);
}

// ---------------------------------------------------------------------------
// K1: Haar wavelet -> fused_t (bf16, [b][hw][ch], ch K-contiguous) + hf channel
// sums via atomicAdd. Grid split by (h2, q-chunk): 2048 blocks -> 4 blocks/CU
// (LDS-capped), 16 waves/CU for latency hiding on the 192 MiB of traffic.
// float4 reads; LDS transpose (odd strides 66/198 = conflict-free u16 writes);
// dwordx4 copy-out.
// ---------------------------------------------------------------------------
__global__ __launch_bounds__(256) void k1_wavelet(const float* __restrict__ x,
                                                  unsigned short* __restrict__ fused_t,
                                                  float* __restrict__ chanSums) {
  __shared__ unsigned short ll_s[64 * 66];   // [w2][ch-chunk], stride 66 u16
  __shared__ unsigned short hf_s[64 * 198];  // [w2][3*ch-chunk], stride 198 u16
  const int tid = threadIdx.x;
  const int h2 = blockIdx.x >> 2;
  const int q  = blockIdx.x & 3;   // 64-src-channel chunk
  const int b  = blockIdx.y;
  const int w4 = tid & 31;   // 32 lanes x float4 = full 128-wide row
  const int grp = tid >> 5;  // 8 channel groups
  const float* xb = x + (size_t)b * C1_ * H_ * W_;
  const size_t rowbase = ((size_t)b * HW_ + (size_t)h2 * 64) * KDIM;

#pragma unroll
  for (int i = 0; i < 8; ++i) {
    int cl = grp * 8 + i;
    int c  = q * 64 + cl;
    const float* xp = xb + (size_t)c * (H_ * W_) + (2 * h2) * W_ + 4 * w4;
    float4 r0 = *(const float4*)xp;          // x00a,x01a,x00b,x01b
    float4 r1 = *(const float4*)(xp + W_);   // x10a,x11a,x10b,x11b
    {
      float x00 = r0.x, x01 = r0.y, x10 = r1.x, x11 = r1.y;
      float LL = 0.5f * (x00 + x01 + x10 + x11);
      float LH = 0.5f * (x00 + x01 - x10 - x11);
      float HL = 0.5f * (x00 - x01 + x10 - x11);
      float HH = 0.5f * (x00 - x01 - x10 + x11);
      int w2 = 2 * w4;
      ll_s[w2 * 66 + cl]          = f2bf(LL);
      hf_s[w2 * 198 + 3 * cl + 0] = f2bf(LH);
      hf_s[w2 * 198 + 3 * cl + 1] = f2bf(HL);
      hf_s[w2 * 198 + 3 * cl + 2] = f2bf(HH);
    }
    {
      float x00 = r0.z, x01 = r0.w, x10 = r1.z, x11 = r1.w;
      float LL = 0.5f * (x00 + x01 + x10 + x11);
      float LH = 0.5f * (x00 + x01 - x10 - x11);
      float HL = 0.5f * (x00 - x01 + x10 - x11);
      float HH = 0.5f * (x00 - x01 - x10 + x11);
      int w2 = 2 * w4 + 1;
      ll_s[w2 * 66 + cl]          = f2bf(LL);
      hf_s[w2 * 198 + 3 * cl + 0] = f2bf(LH);
      hf_s[w2 * 198 + 3 * cl + 1] = f2bf(HL);
      hf_s[w2 * 198 + 3 * cl + 2] = f2bf(HH);
    }
  }
  __syncthreads();
  // LL copy-out: 64 rows x 128 B = 512 dwordx4 stores, 2 sweeps
  {
    const unsigned int* lw = (const unsigned int*)ll_s;
#pragma unroll
    for (int t = 0; t < 2; ++t) {
      int idx = t * 256 + tid;        // 0..511
      int row = idx >> 3, s = idx & 7;
      int base = row * 33 + s * 4;
      uint4 v;
      v.x = lw[base]; v.y = lw[base + 1]; v.z = lw[base + 2]; v.w = lw[base + 3];
      *(uint4*)((char*)(fused_t + rowbase + (size_t)row * KDIM + q * 64) + s * 16) = v;
    }
  }
  // HF copy-out: 64 rows x 384 B = 1536 dwordx4 stores, 6 sweeps
  {
    const unsigned int* hv = (const unsigned int*)hf_s;
#pragma unroll
    for (int t = 0; t < 6; ++t) {
      int idx = t * 256 + tid;        // 0..1535
      int row = idx / 24, s = idx - row * 24;
      int base = row * 99 + s * 4;
      uint4 v;
      v.x = hv[base]; v.y = hv[base + 1]; v.z = hv[base + 2]; v.w = hv[base + 3];
      *(uint4*)((char*)(fused_t + rowbase + (size_t)row * KDIM + 256 + q * 192) + s * 16) = v;
    }
  }
  // hf channel sums from the LDS tile
  if (tid < 192) {
    float s = 0.f;
#pragma unroll 8
    for (int r = 0; r < 64; ++r) s += bf2f(hf_s[r * 198 + tid]);
    atomicAdd(&chanSums[b * CHF_ + q * 192 + tid], s);
  }
}

// ---------------------------------------------------------------------------
// K2: SE MLP (mean -> relu(w1) -> sigmoid(w2)) + scale array + BN affine
// precompute. One block per batch; chanSums fully reduced by k1's atomics.
// ---------------------------------------------------------------------------
__global__ __launch_bounds__(256) void k2_mlp(const float* __restrict__ chanSums,
                                              const float* __restrict__ w1,
                                              const float* __restrict__ w2,
                                              const float* __restrict__ gamma,
                                              const float* __restrict__ beta,
                                              const float* __restrict__ mean,
                                              const float* __restrict__ var,
                                              float* __restrict__ scaleArr,
                                              float* __restrict__ bnA,
                                              float* __restrict__ bnB) {
  __shared__ float mean_s[CHF_];
  __shared__ float part_s[192];
  __shared__ float y1_s[MID_];
  const int tid = threadIdx.x;
  const int b = blockIdx.x;
  for (int k = tid; k < CHF_; k += 256)
    mean_s[k] = chanSums[b * CHF_ + k] * (1.0f / 4096.0f);
  __syncthreads();
  if (tid < 192) {  // 4 threads per output m, 192-deep partials
    int m = tid >> 2, p = tid & 3;
    const float* wr = w1 + (size_t)m * CHF_ + p * 192;
    const float* ms = mean_s + p * 192;
    float s = 0.f;
#pragma unroll 8
    for (int k = 0; k < 192; ++k) s += ms[k] * wr[k];
    part_s[tid] = s;
  }
  __syncthreads();
  if (tid < MID_) {
    float s = part_s[4 * tid] + part_s[4 * tid + 1] + part_s[4 * tid + 2] + part_s[4 * tid + 3];
    y1_s[tid] = fmaxf(s, 0.f);
  }
  __syncthreads();
  for (int c = tid; c < CHF_; c += 256) {
    const float* wr = w2 + (size_t)c * MID_;
    float d = 0.f;
#pragma unroll
    for (int m = 0; m < MID_; ++m) d += y1_s[m] * wr[m];
    scaleArr[b * KDIM + 256 + c] = 1.0f / (1.0f + __expf(-d));
  }
  scaleArr[b * KDIM + tid] = 1.0f;  // LL channels unscaled (tid covers 0..255)
  if (b == 0) {
    for (int o = tid; o < C2_; o += 256) {
      float inv = rsqrtf(var[o] + 1e-5f);
      float a = gamma[o] * inv;
      bnA[o] = a;
      bnB[o] = beta[o] - mean[o] * a;
    }
  }
}

// ---------------------------------------------------------------------------
// K2b: fold SE scale into per-batch bf16 weights: conv_ws[b][o][c]
// ---------------------------------------------------------------------------
__global__ __launch_bounds__(256) void k2b_scalew(const float* __restrict__ conv_w,
                                                  const float* __restrict__ scaleArr,
                                                  unsigned short* __restrict__ conv_ws) {
  int idx = blockIdx.x * 256 + threadIdx.x;  // 1,048,576 groups of 4 elements
  int b = idx >> 17;
  int rem = idx & 131071;
  int o = rem >> 8;
  int c = (rem & 255) * 4;
  float4 wv = *(const float4*)(conv_w + (size_t)o * KDIM + c);
  float4 sv = *(const float4*)(scaleArr + b * KDIM + c);
  ushort4 r;
  r.x = f2bf(wv.x * sv.x);
  r.y = f2bf(wv.y * sv.y);
  r.z = f2bf(wv.z * sv.z);
  r.w = f2bf(wv.w * sv.w);
  *(ushort4*)(conv_ws + ((size_t)(b * C2_ + o) * KDIM + c)) = r;
}

// ---------------------------------------------------------------------------
// K3: per-batch GEMM  C[o][hw] = sum_c conv_ws[o][c] * fused_t[hw][c]
// (M=512, N=4096, K=1024). Block tile 128m x 256n, BK=64; 4 waves in 2x2, each
// wave 64m x 128n (af2 + bf4 = 6 ds_read_b128 per 8 MFMAs — 25% fewer LDS
// reads/FLOP than the 64x64 wave tile; k3 is LDS-read-bound). XOR-swizzled
// 128 B LDS rows; global_load_lds width=16 staging. Grid = 512 blocks = 2/CU
// exact. Epilogue: BN affine + SiLU.
// C/D layout (m74/m101): col=lane&31 (hw), row=(reg&3)+8*(reg>>2)+4*(lane>>5).
// ---------------------------------------------------------------------------
typedef const __attribute__((address_space(1))) unsigned int* gas_u32p;
typedef __attribute__((address_space(3))) unsigned int* las_u32p;
__device__ __forceinline__ void async_ld16(const void* g, void* l) {
  __builtin_amdgcn_global_load_lds((gas_u32p)g, (las_u32p)l, 16, 0, 0);
}

__global__ __launch_bounds__(256, 2) void k3_gemm(const unsigned short* __restrict__ conv_ws,
                                                  const unsigned short* __restrict__ fused_t,
                                                  const float* __restrict__ bnA,
                                                  const float* __restrict__ bnB,
                                                  float* __restrict__ out) {
  __shared__ short As[128 * 64];  // [m][k], 128 B rows, k-blocks XOR-swizzled
  __shared__ short Bs[256 * 64];  // [n][k], 128 B rows
  const int tid  = threadIdx.x;
  const int lane = tid & 63;
  const int wave = tid >> 6;
  const int b  = blockIdx.z;
  const int m0 = blockIdx.y * 128;  // o tile
  const int n0 = blockIdx.x * 256;  // hw tile
  const char* Abase = (const char*)(conv_ws + (size_t)b * C2_ * KDIM);
  const char* Bbase = (const char*)(fused_t + (size_t)b * HW_ * KDIM);
  // staging: each async instr covers 8 rows (8 lanes x 16 B per 128 B row);
  // lane fetches global k-block (kb ^ rloc) into LDS slot kb of row rloc.
  const int rloc = lane >> 3;        // row within 8-row group
  const int kb   = lane & 7;         // 16 B k-block within row
  const int kbsw = kb ^ rloc;        // swizzled global k-block
  const char* gA = Abase + (size_t)(m0 + wave * 32 + rloc) * (KDIM * 2) + kbsw * 16;
  const char* gB = Bbase + (size_t)(n0 + wave * 64 + rloc) * (KDIM * 2) + kbsw * 16;
  short* lA = As + (wave * 32) * 64;   // 4 instrs x 8 rows = 32 rows/wave
  short* lB = Bs + (wave * 64) * 64;   // 8 instrs x 8 rows = 64 rows/wave
  const int wm = wave & 1, wn = wave >> 1;
  const int r  = lane & 31;          // fragment row (m or n)
  const int hi = lane >> 5;
  const int sw = r & 7;              // un-swizzle key for this row
  f32x16 acc[2][4] = {};

  for (int k0 = 0; k0 < KDIM; k0 += 64) {
#pragma unroll
    for (int t = 0; t < 4; ++t)
      async_ld16(gA + (size_t)t * 8 * (KDIM * 2), lA + t * 8 * 64);
#pragma unroll
    for (int t = 0; t < 8; ++t)
      async_ld16(gB + (size_t)t * 8 * (KDIM * 2), lB + t * 8 * 64);
    gA += 128; gB += 128;
    __syncthreads();  // drains vmcnt -> LDS tiles ready
#pragma unroll
    for (int ks = 0; ks < 4; ++ks) {
      const int kbg = 2 * ks + hi;       // global k-block this fragment wants
      const int ko  = (kbg ^ sw) << 3;   // short offset within the row
      short8 af[2], bf[4];
#pragma unroll
      for (int im = 0; im < 2; ++im)
        af[im] = *(const short8*)(As + (wm * 64 + im * 32 + r) * 64 + ko);
#pragma unroll
      for (int in = 0; in < 4; ++in)
        bf[in] = *(const short8*)(Bs + (wn * 128 + in * 32 + r) * 64 + ko);
#pragma unroll
      for (int im = 0; im < 2; ++im)
#pragma unroll
        for (int in = 0; in < 4; ++in)
          acc[im][in] = __builtin_amdgcn_mfma_f32_32x32x16_bf16(af[im], bf[in], acc[im][in], 0, 0, 0);
    }
    __syncthreads();  // all waves done reading before next stage overwrites
  }

  // epilogue: BN affine + SiLU
  float* outb = out + (size_t)b * C2_ * HW_;
#pragma unroll
  for (int im = 0; im < 2; ++im) {
#pragma unroll
    for (int in = 0; in < 4; ++in) {
      int hw = n0 + wn * 128 + in * 32 + r;
#pragma unroll
      for (int reg = 0; reg < 16; ++reg) {
        int o = m0 + wm * 64 + im * 32 + (reg & 3) + 8 * (reg >> 2) + 4 * hi;
        float a = bnA[o], c0 = bnB[o];
        float z = acc[im][in][reg] * a + c0;
        outb[(size_t)o * HW_ + hw] = z / (1.0f + __expf(-z));
      }
    }
  }
}

// ---------------------------------------------------------------------------
extern "C" void kernel_launch(void* const* d_in, const int* in_sizes, int n_in,
                              void* d_out, int out_size, void* d_ws, size_t ws_size,
                              hipStream_t stream) {
  const float* x      = (const float*)d_in[0];
  const float* w1     = (const float*)d_in[1];
  const float* w2     = (const float*)d_in[2];
  const float* conv_w = (const float*)d_in[3];
  const float* gamma  = (const float*)d_in[4];
  const float* beta   = (const float*)d_in[5];
  const float* mean   = (const float*)d_in[6];
  const float* var    = (const float*)d_in[7];
  float* out = (float*)d_out;

  char* ws = (char*)d_ws;
  unsigned short* fused_t = (unsigned short*)ws;                       // 64 MiB bf16 [b][hw][c]
  unsigned short* conv_ws = (unsigned short*)(ws + (size_t)67108864);  // 8 MiB bf16 [b][o][c]
  float* chanSums = (float*)(ws + (size_t)75497472);                   // 8x768 f32
  float* scaleArr = (float*)(ws + (size_t)75522048);                   // 8x1024 f32
  float* bnA      = (float*)(ws + (size_t)75554816);                   // 512 f32
  float* bnB      = (float*)(ws + (size_t)75556864);                   // 512 f32

  hipMemsetAsync(chanSums, 0, B_ * CHF_ * sizeof(float), stream);
  k1_wavelet<<<dim3(256, 8), 256, 0, stream>>>(x, fused_t, chanSums);
  k2_mlp<<<dim3(8), 256, 0, stream>>>(chanSums, w1, w2, gamma, beta, mean, var,
                                      scaleArr, bnA, bnB);
  k2b_scalew<<<dim3(4096), 256, 0, stream>>>(conv_w, scaleArr, conv_ws);
  k3_gemm<<<dim3(16, 4, 8), 256, 0, stream>>>(conv_ws, fused_t, bnA, bnB, out);
}